// Round 1
// baseline (1566.589 us; speedup 1.0000x reference)
//
#include <hip/hip_runtime.h>
#include <cstdint>
#include <cstddef>

// Int8Linear + exact GELU on MI355X.
// y[m][n] = gelu( scale[n] * sum_k x[m][k]*Wq[n][k] + b[n] )
// M=8192 (B*S), N=11008 (DOUT), K=4096 (DIN).
//
// Strategy: bf16 MFMA GEMM (m97-ladder structure).
//  - Wq (int8 range) -> bf16 is EXACT; scale applied in fp32 epilogue.
//  - x fp32 -> bf16 (RNE) is the only rounding source; well within threshold.
//  - Path A (ws_size >= 150MB): pre-convert both operands into d_ws, then
//    global_load_lds(width=16) staged 128x128x32 tile GEMM.
//  - Path B (fallback): same tile GEMM but VALU-staged with inline conversion.

#define Msz 8192
#define Nsz 11008
#define Ksz 4096
#define BM 128
#define BN 128
#define BK 32

typedef __attribute__((ext_vector_type(8))) short short8;
typedef __attribute__((ext_vector_type(4))) float floatx4;

// fp32 -> bf16 round-to-nearest-even (inputs finite; no NaN path needed)
__device__ __forceinline__ unsigned int f2bf(float f) {
  unsigned int u = __builtin_bit_cast(unsigned int, f);
  unsigned int r = u + 0x7FFFu + ((u >> 16) & 1u);
  return r >> 16;  // low 16 bits hold the bf16 pattern
}

__device__ __forceinline__ void async16(const void* g, void* l) {
  __builtin_amdgcn_global_load_lds(
      (const __attribute__((address_space(1))) void*)g,
      (__attribute__((address_space(3))) void*)l, 16, 0, 0);
}

__global__ __launch_bounds__(256) void cvt_f32_bf16(
    const float4* __restrict__ in, uint4* __restrict__ out) {
  const size_t i = (size_t)blockIdx.x * 256 + threadIdx.x;
  const float4 a = in[2 * i];
  const float4 b = in[2 * i + 1];
  uint4 o;
  o.x = f2bf(a.x) | (f2bf(a.y) << 16);
  o.y = f2bf(a.z) | (f2bf(a.w) << 16);
  o.z = f2bf(b.x) | (f2bf(b.y) << 16);
  o.w = f2bf(b.z) | (f2bf(b.w) << 16);
  out[i] = o;
}

__global__ __launch_bounds__(256) void cvt_i32_bf16(
    const int4* __restrict__ in, uint4* __restrict__ out) {
  const size_t i = (size_t)blockIdx.x * 256 + threadIdx.x;
  const int4 a = in[2 * i];
  const int4 b = in[2 * i + 1];
  uint4 o;
  o.x = f2bf((float)a.x) | (f2bf((float)a.y) << 16);
  o.y = f2bf((float)a.z) | (f2bf((float)a.w) << 16);
  o.z = f2bf((float)b.x) | (f2bf((float)b.y) << 16);
  o.w = f2bf((float)b.z) | (f2bf((float)b.w) << 16);
  out[i] = o;
}

// PRE=1: Ap/Bp are pre-converted bf16 (row-major [M][K] / [N][K])
// PRE=0: Ap is fp32 x, Bp is int32 Wq; convert inline during staging
template <int PRE>
__global__ __launch_bounds__(256) void int8lin_gemm(
    const void* __restrict__ Ap, const void* __restrict__ Bp,
    const float* __restrict__ scale, const float* __restrict__ bias,
    float* __restrict__ out) {
  __shared__ unsigned short sA[BM * BK];  // 8 KB
  __shared__ unsigned short sB[BN * BK];  // 8 KB

  const int tid = threadIdx.x;
  const int wave = tid >> 6;
  const int lane = tid & 63;
  const int bn0 = blockIdx.x * BN;
  const int bm0 = blockIdx.y * BM;
  const int mw = (wave >> 1) * 64;  // wave's row quadrant
  const int nw = (wave & 1) * 64;   // wave's col quadrant

  floatx4 acc[4][4];
#pragma unroll
  for (int i = 0; i < 4; ++i)
#pragma unroll
    for (int j = 0; j < 4; ++j) acc[i][j] = (floatx4)0.f;

  for (int k0 = 0; k0 < Ksz; k0 += BK) {
    if (PRE) {
      const unsigned short* Ab = (const unsigned short*)Ap;
      const unsigned short* Bb = (const unsigned short*)Bp;
      const int kof = (lane & 3) * 8;
#pragma unroll
      for (int iss = 0; iss < 2; ++iss) {
        // wave-uniform LDS base + lane*16B contiguity holds:
        // lds byte = (wave*32+iss*16)*64 + (lane>>2)*64 + (lane&3)*16 = base + lane*16
        const int row = wave * 32 + iss * 16 + (lane >> 2);
        async16(Ab + (size_t)(bm0 + row) * Ksz + k0 + kof, &sA[row * BK + kof]);
        async16(Bb + (size_t)(bn0 + row) * Ksz + k0 + kof, &sB[row * BK + kof]);
      }
    } else {
      const float* Af = (const float*)Ap;
      const int* Bi = (const int*)Bp;
#pragma unroll
      for (int it = 0; it < 4; ++it) {
        const int f = tid + it * 256;  // float4/int4 linear index over 128x8
        const int row = f >> 3;
        const int c4 = (f & 7) * 4;
        const float4 v = *(const float4*)(Af + (size_t)(bm0 + row) * Ksz + k0 + c4);
        uint2 p;
        p.x = f2bf(v.x) | (f2bf(v.y) << 16);
        p.y = f2bf(v.z) | (f2bf(v.w) << 16);
        *(uint2*)&sA[row * BK + c4] = p;
        const int4 w = *(const int4*)(Bi + (size_t)(bn0 + row) * Ksz + k0 + c4);
        uint2 q;
        q.x = f2bf((float)w.x) | (f2bf((float)w.y) << 16);
        q.y = f2bf((float)w.z) | (f2bf((float)w.w) << 16);
        *(uint2*)&sB[row * BK + c4] = q;
      }
    }
    __syncthreads();

    short8 af[4], bfr[4];
    const int kof2 = (lane >> 4) * 8;
#pragma unroll
    for (int i = 0; i < 4; ++i) {
      af[i] = *(const short8*)&sA[(mw + i * 16 + (lane & 15)) * BK + kof2];
      bfr[i] = *(const short8*)&sB[(nw + i * 16 + (lane & 15)) * BK + kof2];
    }
#pragma unroll
    for (int i = 0; i < 4; ++i)
#pragma unroll
      for (int j = 0; j < 4; ++j)
        acc[i][j] =
            __builtin_amdgcn_mfma_f32_16x16x32_bf16(af[i], bfr[j], acc[i][j], 0, 0, 0);
    __syncthreads();
  }

  // Epilogue: C/D layout col=lane&15, row=(lane>>4)*4+reg (m89/m91 verified)
#pragma unroll
  for (int j = 0; j < 4; ++j) {
    const int col = bn0 + nw + j * 16 + (lane & 15);
    const float s = scale[col];
    const float bb = bias[col];
#pragma unroll
    for (int i = 0; i < 4; ++i) {
      const int row0 = bm0 + mw + i * 16 + (lane >> 4) * 4;
#pragma unroll
      for (int r = 0; r < 4; ++r) {
        float v = acc[i][j][r] * s + bb;
        v = 0.5f * v * (1.0f + erff(v * 0.7071067811865476f));
        out[(size_t)(row0 + r) * Nsz + col] = v;
      }
    }
  }
}

extern "C" void kernel_launch(void* const* d_in, const int* in_sizes, int n_in,
                              void* d_out, int out_size, void* d_ws, size_t ws_size,
                              hipStream_t stream) {
  const float* x = (const float*)d_in[0];        // [M][K] fp32
  const int* Wq = (const int*)d_in[1];           // [N][K] int32 (int8 values)
  const float* scale = (const float*)d_in[2];    // [N]
  const float* bias = (const float*)d_in[3];     // [N]
  float* out = (float*)d_out;                    // [M][N] fp32

  const size_t nx = (size_t)Msz * Ksz;  // 33,554,432
  const size_t nwq = (size_t)Nsz * Ksz; // 45,088,768
  dim3 grid(Nsz / BN, Msz / BM);        // 86 x 64
  dim3 block(256);

  if (ws_size >= (nx + nwq) * sizeof(unsigned short)) {
    unsigned short* xbf = (unsigned short*)d_ws;
    unsigned short* wbf = xbf + nx;
    cvt_f32_bf16<<<dim3((unsigned)(nx / (8 * 256))), block, 0, stream>>>(
        (const float4*)x, (uint4*)xbf);
    cvt_i32_bf16<<<dim3((unsigned)(nwq / (8 * 256))), block, 0, stream>>>(
        (const int4*)Wq, (uint4*)wbf);
    int8lin_gemm<1><<<grid, block, 0, stream>>>(xbf, wbf, scale, bias, out);
  } else {
    int8lin_gemm<0><<<grid, block, 0, stream>>>(x, Wq, scale, bias, out);
  }
}

// Round 2
// 1167.946 us; speedup vs baseline: 1.3413x; 1.3413x over previous
//
#include <hip/hip_runtime.h>
#include <cstdint>
#include <cstddef>

// Int8Linear + exact GELU on MI355X — int8 MFMA path.
// y[m][n] = gelu( scale[n] * sum_k x[m][k]*Wq[n][k] + b[n] )
// M=8192, N=11008, K=4096.
//
// Round 2: exploit that Wq is already int8-valued. Quantize x per-row to int8
// (only error source; predicted absmax ~5 vs threshold 9.12), run
// mfma_i32_16x16x64_i8 (exact int32 accum, 2x bf16 rate, half the K-iters of
// the round-1 bf16 kernel at identical per-iter staging cost), dequant in the
// fp32 epilogue: y = gelu(acc * qs[m] * scale[n] + b[n]).

#define Msz 8192
#define Nsz 11008
#define Ksz 4096
#define BM 128
#define BN 128
#define BKB 64  // K-bytes per LDS row (64 i8 = BK)

typedef __attribute__((ext_vector_type(4))) int int4v;
typedef __attribute__((ext_vector_type(8))) short short8;
typedef __attribute__((ext_vector_type(4))) float floatx4;

__device__ __forceinline__ void async16(const void* g, void* l) {
  __builtin_amdgcn_global_load_lds(
      (const __attribute__((address_space(1))) void*)g,
      (__attribute__((address_space(3))) void*)l, 16, 0, 0);
}

// ---- pre-pass 1: per-row symmetric int8 quantization of x -----------------
// one block per row of 4096 floats; unit-stride float4 loads, dword stores.
__global__ __launch_bounds__(256) void quant_x(
    const float* __restrict__ x, signed char* __restrict__ xq,
    float* __restrict__ qs) {
  const int row = blockIdx.x;
  const int tid = threadIdx.x;
  const int lane = tid & 63;
  const int wave = tid >> 6;
  const float4* xr = (const float4*)(x + (size_t)row * Ksz);

  float4 v[4];
  float m = 0.f;
#pragma unroll
  for (int t = 0; t < 4; ++t) {
    v[t] = xr[tid + t * 256];
    m = fmaxf(m, fmaxf(fmaxf(fabsf(v[t].x), fabsf(v[t].y)),
                       fmaxf(fabsf(v[t].z), fabsf(v[t].w))));
  }
#pragma unroll
  for (int o = 32; o > 0; o >>= 1) m = fmaxf(m, __shfl_down(m, o));
  __shared__ float sm[4];
  if (lane == 0) sm[wave] = m;
  __syncthreads();
  const float am = fmaxf(fmaxf(sm[0], sm[1]), fmaxf(sm[2], sm[3]));
  const float rs = am > 0.f ? 127.0f / am : 0.f;
  if (tid == 0) qs[row] = am * (1.0f / 127.0f);

  unsigned* outd = (unsigned*)(xq + (size_t)row * Ksz);
#pragma unroll
  for (int t = 0; t < 4; ++t) {
    int q0 = __float2int_rn(fminf(fmaxf(v[t].x * rs, -127.f), 127.f));
    int q1 = __float2int_rn(fminf(fmaxf(v[t].y * rs, -127.f), 127.f));
    int q2 = __float2int_rn(fminf(fmaxf(v[t].z * rs, -127.f), 127.f));
    int q3 = __float2int_rn(fminf(fmaxf(v[t].w * rs, -127.f), 127.f));
    outd[tid + t * 256] = (unsigned)(q0 & 255) | ((unsigned)(q1 & 255) << 8) |
                          ((unsigned)(q2 & 255) << 16) | ((unsigned)q3 << 24);
  }
}

// ---- pre-pass 2: pack Wq int32 -> int8 ------------------------------------
__global__ __launch_bounds__(256) void pack_w(const int4* __restrict__ w,
                                              unsigned* __restrict__ o) {
  const unsigned gid = blockIdx.x * 256 + threadIdx.x;
  const unsigned stride = 11008u * 256u;  // gridDim*block
#pragma unroll
  for (int t = 0; t < 4; ++t) {
    const unsigned idx = gid + t * stride;
    const int4 a = w[idx];
    o[idx] = (unsigned)(a.x & 255) | ((unsigned)(a.y & 255) << 8) |
             ((unsigned)(a.z & 255) << 16) | ((unsigned)a.w << 24);
  }
}

// ---- main GEMM: int8 MFMA, m97 staging structure --------------------------
__global__ __launch_bounds__(256) void gemm_i8(
    const signed char* __restrict__ A8,  // [M][K] int8
    const signed char* __restrict__ B8,  // [N][K] int8
    const float* __restrict__ qs,        // [M] per-row x scales
    const float* __restrict__ scale, const float* __restrict__ bias,
    float* __restrict__ out) {
  __shared__ signed char sA[BM * BKB];  // 8 KB
  __shared__ signed char sB[BN * BKB];  // 8 KB

  const int tid = threadIdx.x;
  const int wave = tid >> 6;
  const int lane = tid & 63;

  // N-panel swizzle (8 N-blocks wide, M fastest) to compact the in-flight
  // working set for L2/L3. 86 = 10*8 + 6.
  const int lbid = blockIdx.x;
  int bx, by;
  if (lbid < 5120) {
    const int p = lbid >> 9;       // panel of 8*64 blocks
    const int r = lbid & 511;
    bx = p * 8 + (r >> 6);
    by = r & 63;
  } else {
    const int r = lbid - 5120;
    bx = 80 + (r >> 6);
    by = r & 63;
  }
  const int bn0 = bx * BN;
  const int bm0 = by * BM;
  const int mw = (wave >> 1) * 64;
  const int nw = (wave & 1) * 64;

  int4v acc[4][4];
#pragma unroll
  for (int i = 0; i < 4; ++i)
#pragma unroll
    for (int j = 0; j < 4; ++j) acc[i][j] = (int4v)0;

  const int chunk = (lane & 3) * 16;
  for (int k0 = 0; k0 < Ksz; k0 += BKB) {
#pragma unroll
    for (int iss = 0; iss < 2; ++iss) {
      // LDS byte = row*64 + chunk = wave_base + lane*16 (contiguity holds)
      const int row = wave * 32 + iss * 16 + (lane >> 2);
      async16(A8 + (size_t)(bm0 + row) * Ksz + k0 + chunk, &sA[row * BKB + chunk]);
      async16(B8 + (size_t)(bn0 + row) * Ksz + k0 + chunk, &sB[row * BKB + chunk]);
    }
    __syncthreads();

    int4v af[4], bfr[4];
    const int kof = (lane >> 4) * 16;  // 16 consecutive i8 per lane-group
#pragma unroll
    for (int i = 0; i < 4; ++i) {
      af[i] = *(const int4v*)&sA[(mw + i * 16 + (lane & 15)) * BKB + kof];
      bfr[i] = *(const int4v*)&sB[(nw + i * 16 + (lane & 15)) * BKB + kof];
    }
#pragma unroll
    for (int i = 0; i < 4; ++i)
#pragma unroll
      for (int j = 0; j < 4; ++j)
        acc[i][j] =
            __builtin_amdgcn_mfma_i32_16x16x64_i8(af[i], bfr[j], acc[i][j], 0, 0, 0);
    __syncthreads();
  }

  // Epilogue. C/D layout: col=lane&15, row=(lane>>4)*4+reg (dtype-independent)
  float qsr[4][4];
#pragma unroll
  for (int i = 0; i < 4; ++i) {
    const int row0 = bm0 + mw + i * 16 + (lane >> 4) * 4;
#pragma unroll
    for (int r = 0; r < 4; ++r) qsr[i][r] = qs[row0 + r];
  }
#pragma unroll
  for (int j = 0; j < 4; ++j) {
    const int col = bn0 + nw + j * 16 + (lane & 15);
    const float s = scale[col];
    const float bb = bias[col];
#pragma unroll
    for (int i = 0; i < 4; ++i) {
      const int row0 = bm0 + mw + i * 16 + (lane >> 4) * 4;
#pragma unroll
      for (int r = 0; r < 4; ++r) {
        float v = (float)acc[i][j][r] * (qsr[i][r] * s) + bb;
        v = 0.5f * v * (1.0f + erff(v * 0.7071067811865476f));
        out[(size_t)(row0 + r) * Nsz + col] = v;
      }
    }
  }
}

// ---- fallback bf16 GEMM (inline conversion) if ws is too small ------------
__device__ __forceinline__ unsigned int f2bf(float f) {
  unsigned int u = __builtin_bit_cast(unsigned int, f);
  unsigned int r = u + 0x7FFFu + ((u >> 16) & 1u);
  return r >> 16;
}

__global__ __launch_bounds__(256) void gemm_bf16_inline(
    const float* __restrict__ Af, const int* __restrict__ Bi,
    const float* __restrict__ scale, const float* __restrict__ bias,
    float* __restrict__ out) {
  __shared__ unsigned short sA[BM * 32];
  __shared__ unsigned short sB[BN * 32];
  const int tid = threadIdx.x;
  const int wave = tid >> 6;
  const int lane = tid & 63;
  const int bn0 = blockIdx.x * BN;
  const int bm0 = blockIdx.y * BM;
  const int mw = (wave >> 1) * 64;
  const int nw = (wave & 1) * 64;
  floatx4 acc[4][4];
#pragma unroll
  for (int i = 0; i < 4; ++i)
#pragma unroll
    for (int j = 0; j < 4; ++j) acc[i][j] = (floatx4)0.f;
  for (int k0 = 0; k0 < Ksz; k0 += 32) {
#pragma unroll
    for (int it = 0; it < 4; ++it) {
      const int f = tid + it * 256;
      const int row = f >> 3;
      const int c4 = (f & 7) * 4;
      const float4 v = *(const float4*)(Af + (size_t)(bm0 + row) * Ksz + k0 + c4);
      uint2 p;
      p.x = f2bf(v.x) | (f2bf(v.y) << 16);
      p.y = f2bf(v.z) | (f2bf(v.w) << 16);
      *(uint2*)&sA[row * 32 + c4] = p;
      const int4 w = *(const int4*)(Bi + (size_t)(bm0 + row) * Ksz + k0 + c4);
      const int4 w2 = *(const int4*)(Bi + (size_t)(bn0 + row) * Ksz + k0 + c4);
      (void)w;
      uint2 q;
      q.x = f2bf((float)w2.x) | (f2bf((float)w2.y) << 16);
      q.y = f2bf((float)w2.z) | (f2bf((float)w2.w) << 16);
      *(uint2*)&sB[row * 32 + c4] = q;
    }
    __syncthreads();
    short8 af[4], bfr[4];
    const int kof2 = (lane >> 4) * 8;
#pragma unroll
    for (int i = 0; i < 4; ++i) {
      af[i] = *(const short8*)&sA[(mw + i * 16 + (lane & 15)) * 32 + kof2];
      bfr[i] = *(const short8*)&sB[(nw + i * 16 + (lane & 15)) * 32 + kof2];
    }
#pragma unroll
    for (int i = 0; i < 4; ++i)
#pragma unroll
      for (int j = 0; j < 4; ++j)
        acc[i][j] =
            __builtin_amdgcn_mfma_f32_16x16x32_bf16(af[i], bfr[j], acc[i][j], 0, 0, 0);
    __syncthreads();
  }
#pragma unroll
  for (int j = 0; j < 4; ++j) {
    const int col = bn0 + nw + j * 16 + (lane & 15);
    const float s = scale[col];
    const float bb = bias[col];
#pragma unroll
    for (int i = 0; i < 4; ++i) {
      const int row0 = bm0 + mw + i * 16 + (lane >> 4) * 4;
#pragma unroll
      for (int r = 0; r < 4; ++r) {
        float v = acc[i][j][r] * s + bb;
        v = 0.5f * v * (1.0f + erff(v * 0.7071067811865476f));
        out[(size_t)(row0 + r) * Nsz + col] = v;
      }
    }
  }
}

extern "C" void kernel_launch(void* const* d_in, const int* in_sizes, int n_in,
                              void* d_out, int out_size, void* d_ws, size_t ws_size,
                              hipStream_t stream) {
  const float* x = (const float*)d_in[0];      // [M][K] fp32
  const int* Wq = (const int*)d_in[1];         // [N][K] int32 (int8 values)
  const float* scale = (const float*)d_in[2];  // [N]
  const float* bias = (const float*)d_in[3];   // [N]
  float* out = (float*)d_out;                  // [M][N] fp32

  const size_t nx = (size_t)Msz * Ksz;   // 33,554,432
  const size_t nwq = (size_t)Nsz * Ksz;  // 45,088,768
  const size_t need = nx + nwq + Msz * sizeof(float);

  if (ws_size >= need) {
    signed char* xq = (signed char*)d_ws;
    signed char* wp = xq + nx;
    float* qsd = (float*)(wp + nwq);
    quant_x<<<dim3(Msz), dim3(256), 0, stream>>>(x, xq, qsd);
    pack_w<<<dim3((unsigned)(nwq / (16 * 256))), dim3(256), 0, stream>>>(
        (const int4*)Wq, (unsigned*)wp);
    gemm_i8<<<dim3(Nsz / BN * (Msz / BM)), dim3(256), 0, stream>>>(
        xq, wp, qsd, scale, bias, out);
  } else {
    dim3 grid(Nsz / BN, Msz / BM);
    gemm_bf16_inline<<<grid, dim3(256), 0, stream>>>(x, Wq, scale, bias, out);
  }
}